// Round 11
// baseline (216.917 us; speedup 1.0000x reference)
//
#include <hip/hip_runtime.h>
#include <hip/hip_fp16.h>

// GCN 2-layer. fp16 MFMA GEMM1; agg1 fused with MFMA gemm2 (LDS tile);
// fp16 messages, fp32 accumulation; 2-rows-per-instruction dwordx4 gathers
// with csr prefetch. CSR via bucket sort (no global atomics), packed ebuf.
// wcast folded into hist; scanB folded into scanA (last-block pattern).

#define CHUNK 8192   // edges per hist/scatter block
#define BSH   8      // bucket = dst >> 8 (256 nodes per bucket)

typedef _Float16 half8 __attribute__((ext_vector_type(8)));
typedef float f32x4 __attribute__((ext_vector_type(4)));

// ---- 1. per-chunk bucket histogram (LDS atomics only) + weight transpose ----
__global__ __launch_bounds__(256) void k_hist(const int* __restrict__ dst,
    int* __restrict__ hist, int E, int nbuck,
    const float* __restrict__ W1, _Float16* __restrict__ whT,
    const float* __restrict__ W2, _Float16* __restrict__ w2hT,
    int* __restrict__ ticket) {
  __shared__ int h[512];
  const int t = threadIdx.x;
  for (int i = t; i < nbuck; i += 256) h[i] = 0;
  __syncthreads();
  int base = blockIdx.x * CHUNK;
  int lim = base + CHUNK < E ? base + CHUNK : E;
  for (int i = base + t; i < lim; i += 256)
    atomicAdd(&h[dst[i] >> BSH], 1);
  __syncthreads();
  for (int i = t; i < nbuck; i += 256)
    hist[(size_t)blockIdx.x * nbuck + i] = h[i];
  // fused weight prep (blocks 0..16)
  if (blockIdx.x < 16) {           // W1 [256][64] -> whT [64][256]
    int d = blockIdx.x * 4 + (t >> 6);
    int k0 = (t & 63) * 4;
#pragma unroll
    for (int i = 0; i < 4; ++i)
      whT[(size_t)d * 256 + k0 + i] = (_Float16)W1[(size_t)(k0 + i) * 64 + d];
  } else if (blockIdx.x == 16) {   // W2 [64][40] -> w2hT [48][64] (pad 0)
    for (int i = t; i < 48 * 64; i += 256) {
      int dd = i >> 6, k = i & 63;
      w2hT[i] = (_Float16)(dd < 40 ? W2[(size_t)k * 40 + dd] : 0.f);
    }
    if (t == 0) *ticket = 0;       // reset scanA's ticket each call
  }
}

// ---- 2. per-bucket exclusive scan over chunks; last block scans totals ----
__global__ __launch_bounds__(256) void k_scanA(int* __restrict__ hist,
    int* __restrict__ colsum, int* __restrict__ bstart, int* __restrict__ ticket,
    int nchunk, int nbuck, int E) {
  __shared__ int s[512];
  __shared__ int lastdone;
  int b = blockIdx.x, t = threadIdx.x;
  s[t]       = (t < nchunk)       ? hist[(size_t)t * nbuck + b]         : 0;
  s[t + 256] = (t + 256 < nchunk) ? hist[(size_t)(t + 256) * nbuck + b] : 0;
  __syncthreads();
  for (int off = 1; off < 512; off <<= 1) {
    int a0 = (t >= off) ? s[t - off] : 0;
    int a1 = (t + 256 >= off) ? s[t + 256 - off] : 0;
    __syncthreads();
    s[t] += a0; s[t + 256] += a1;
    __syncthreads();
  }
  if (t < nchunk) hist[(size_t)t * nbuck + b] = t ? s[t - 1] : 0;
  if (t + 256 < nchunk) hist[(size_t)(t + 256) * nbuck + b] = s[t + 255];
  if (t == 0) colsum[b] = s[nchunk - 1];
  // last finishing block performs the bucket-total scan (old scanB)
  __threadfence();
  if (t == 0) lastdone = (atomicAdd(ticket, 1) == nbuck - 1);
  __syncthreads();
  if (!lastdone) return;
  __threadfence();
  s[t]       = (t < nbuck)       ? colsum[t]       : 0;
  s[t + 256] = (t + 256 < nbuck) ? colsum[t + 256] : 0;
  __syncthreads();
  for (int off = 1; off < 512; off <<= 1) {
    int a0 = (t >= off) ? s[t - off] : 0;
    int a1 = (t + 256 >= off) ? s[t + 256 - off] : 0;
    __syncthreads();
    s[t] += a0; s[t + 256] += a1;
    __syncthreads();
  }
  if (t < nbuck) bstart[t] = t ? s[t - 1] : 0;
  if (t + 256 < nbuck) bstart[t + 256] = s[t + 255];
  if (t == 0) bstart[nbuck] = E;
}

// ---- 4. scatter edges into bucket-sorted packed ebuf (LDS cursors only) ----
// packed: (src << 8) | (dst & 255)   [src < 2^17]
__global__ __launch_bounds__(256) void k_scatter2(const int* __restrict__ src,
    const int* __restrict__ dst, const int* __restrict__ hist,
    const int* __restrict__ bstart, int* __restrict__ ebuf, int E, int nbuck) {
  __shared__ int cur[512];
  for (int i = threadIdx.x; i < nbuck; i += 256)
    cur[i] = bstart[i] + hist[(size_t)blockIdx.x * nbuck + i];
  __syncthreads();
  int base = blockIdx.x * CHUNK;
  int lim = base + CHUNK < E ? base + CHUNK : E;
  for (int i = base + threadIdx.x; i < lim; i += 256) {
    int d = dst[i];
    int pos = atomicAdd(&cur[d >> BSH], 1);
    ebuf[pos] = (src[i] << 8) | (d & 255);
  }
}

// ---- 5. per-bucket LDS counting sort -> csr, rowptr, dinv ----
__global__ __launch_bounds__(256) void k_csr(const int* __restrict__ ebuf,
    const int* __restrict__ bstart, int* __restrict__ csr, int* __restrict__ rowptr,
    float* __restrict__ dinv, int N, int E, int nbuck) {
  int b = blockIdx.x, t = threadIdx.x;
  int beg = bstart[b], end = bstart[b + 1];
  __shared__ int s[256];
  __shared__ int cur[256];
  s[t] = 0;
  __syncthreads();
  for (int i = beg + t; i < end; i += 256)
    atomicAdd(&s[ebuf[i] & 255], 1);
  __syncthreads();
  int cnt = s[t];
  for (int off = 1; off < 256; off <<= 1) {  // inclusive scan
    int a = (t >= off) ? s[t - off] : 0;
    __syncthreads();
    s[t] += a;
    __syncthreads();
  }
  int ex = t ? s[t - 1] : 0;
  cur[t] = beg + ex;
  int node = (b << BSH) + t;
  if (node < N) {
    rowptr[node] = beg + ex;
    dinv[node] = rsqrtf((float)cnt + 1.0f);  // +1 self-loop
  }
  if (b == 0 && t == 0) rowptr[N] = E;
  __syncthreads();
  for (int i = beg + t; i < end; i += 256) {
    int v = ebuf[i];
    int pos = atomicAdd(&cur[v & 255], 1);
    csr[pos] = (int)((unsigned)v >> 8);
  }
}

// ---- GEMM1 via MFMA f16: wave = 16 rows x 64 cols, K=256; all x loads hoisted ----
__global__ __launch_bounds__(256) void k_gemm1(const float* __restrict__ x,
    const _Float16* __restrict__ whT, const float* __restrict__ dinv,
    __half* __restrict__ h1h, int N) {
  const int l = threadIdx.x & 63;
  const int wid = threadIdx.x >> 6;
  const int r0 = (blockIdx.x * 4 + wid) * 16;
  if (r0 >= N) return;
  const int c0 = l & 15;
  const int q = l >> 4;
  int arow = r0 + c0; if (arow >= N) arow = N - 1;
  const float* xp = x + (size_t)arow * 256 + q * 8;
  float4 xv[8][2];
#pragma unroll
  for (int step = 0; step < 8; ++step) {
    xv[step][0] = *(const float4*)(xp + step * 32);
    xv[step][1] = *(const float4*)(xp + step * 32 + 4);
  }
  f32x4 acc0 = {0.f, 0.f, 0.f, 0.f}, acc1 = {0.f, 0.f, 0.f, 0.f};
  f32x4 acc2 = {0.f, 0.f, 0.f, 0.f}, acc3 = {0.f, 0.f, 0.f, 0.f};
#pragma unroll
  for (int step = 0; step < 8; ++step) {
    const int kb = step * 32 + q * 8;
    half8 aF;
    aF[0] = (_Float16)xv[step][0].x; aF[1] = (_Float16)xv[step][0].y;
    aF[2] = (_Float16)xv[step][0].z; aF[3] = (_Float16)xv[step][0].w;
    aF[4] = (_Float16)xv[step][1].x; aF[5] = (_Float16)xv[step][1].y;
    aF[6] = (_Float16)xv[step][1].z; aF[7] = (_Float16)xv[step][1].w;
    half8 b0 = *(const half8*)(whT + (size_t)(c0)      * 256 + kb);
    half8 b1 = *(const half8*)(whT + (size_t)(c0 + 16) * 256 + kb);
    half8 b2 = *(const half8*)(whT + (size_t)(c0 + 32) * 256 + kb);
    half8 b3 = *(const half8*)(whT + (size_t)(c0 + 48) * 256 + kb);
    acc0 = __builtin_amdgcn_mfma_f32_16x16x32_f16(aF, b0, acc0, 0, 0, 0);
    acc1 = __builtin_amdgcn_mfma_f32_16x16x32_f16(aF, b1, acc1, 0, 0, 0);
    acc2 = __builtin_amdgcn_mfma_f32_16x16x32_f16(aF, b2, acc2, 0, 0, 0);
    acc3 = __builtin_amdgcn_mfma_f32_16x16x32_f16(aF, b3, acc3, 0, 0, 0);
  }
#pragma unroll
  for (int j = 0; j < 4; ++j) {
    int row = r0 + q * 4 + j;
    if (row < N) {
      float dv = dinv[row];
      __half* ph = h1h + (size_t)row * 64 + c0;
      ph[0]  = __float2half(acc0[j] * dv);
      ph[16] = __float2half(acc1[j] * dv);
      ph[32] = __float2half(acc2[j] * dv);
      ph[48] = __float2half(acc3[j] * dv);
    }
  }
}

// add full 16B (8 halfs) of row S at half-offset ro*8 into acc[0..7]
#define HADD8(S, HPTR, STRIDE) { \
  uint4 u_ = *(const uint4*)((HPTR) + (size_t)(S) * (STRIDE) + ro * 8); \
  union { unsigned v; __half2 h; } p0_, p1_, p2_, p3_; \
  p0_.v = u_.x; p1_.v = u_.y; p2_.v = u_.z; p3_.v = u_.w; \
  float2 f0_ = __half22float2(p0_.h), f1_ = __half22float2(p1_.h); \
  float2 f2_ = __half22float2(p2_.h), f3_ = __half22float2(p3_.h); \
  acc[0] += f0_.x; acc[1] += f0_.y; acc[2] += f1_.x; acc[3] += f1_.y; \
  acc[4] += f2_.x; acc[5] += f2_.y; acc[6] += f3_.x; acc[7] += f3_.y; }

// ---- fused agg1 + gemm2: block = 16 dst rows; 8-lane-half row gathers;
//      csr prefetch; hrelu -> LDS tile -> wave0 MFMA -> h2h (stride 40) ----
__global__ __launch_bounds__(256) void k_agg1g2(const __half* __restrict__ h1h,
    const int* __restrict__ rowptr, const int* __restrict__ csr,
    const float* __restrict__ dinv, const float* __restrict__ b1,
    const _Float16* __restrict__ w2hT, __half* __restrict__ h2h, int N) {
  __shared__ _Float16 hl[16][72];
  const int t = threadIdx.x;
  const int r = t & 15;        // lane within quarter
  const int h = r >> 3;        // half-group: row parity
  const int ro = r & 7;        // 16B chunk owner: dims ro*8..+8
  const int qq = (t >> 4) & 3; // quarter within wave
  const int qidx = t >> 4;     // row slot within block
  const int row = blockIdx.x * 16 + qidx;
  const int rowc = row < N ? row : N - 1;
  const int beg = rowptr[rowc], end = (row < N) ? rowptr[rowc + 1] : beg;
  float acc[8] = {};
  if (h == 0) HADD8(rowc, h1h, 64);  // self term, exactly once
  int idx = (beg + r < end) ? csr[beg + r] : 0;
  for (int b = beg; b < end; b += 16) {
    int m = end - b; if (m > 16) m = 16;
    int idxn = (b + 16 + r < end) ? csr[b + 16 + r] : 0;  // prefetch next block
#pragma unroll
    for (int tt = 0; tt < 8; ++tt) {
      int e = 2 * tt + h;
      int s0 = __shfl(idx, qq * 16 + e);
      if (e < m) { HADD8(s0, h1h, 64); }
    }
    idx = idxn;
  }
#pragma unroll
  for (int i = 0; i < 8; ++i) acc[i] += __shfl_xor(acc[i], 8);
  if (h == 0) {
    float4 ba = *(const float4*)(b1 + ro * 8);
    float4 bbv = *(const float4*)(b1 + ro * 8 + 4);
    float dv = dinv[rowc];
    half8 hv;
    hv[0] = (_Float16)fmaxf(dv * acc[0] + ba.x, 0.f);
    hv[1] = (_Float16)fmaxf(dv * acc[1] + ba.y, 0.f);
    hv[2] = (_Float16)fmaxf(dv * acc[2] + ba.z, 0.f);
    hv[3] = (_Float16)fmaxf(dv * acc[3] + ba.w, 0.f);
    hv[4] = (_Float16)fmaxf(dv * acc[4] + bbv.x, 0.f);
    hv[5] = (_Float16)fmaxf(dv * acc[5] + bbv.y, 0.f);
    hv[6] = (_Float16)fmaxf(dv * acc[6] + bbv.z, 0.f);
    hv[7] = (_Float16)fmaxf(dv * acc[7] + bbv.w, 0.f);
    *(half8*)&hl[qidx][ro * 8] = hv;
  }
  __syncthreads();
  if (t >= 64) return;  // wave 0 does the 16x48 GEMM
  const int c0 = t & 15;
  const int q = t >> 4;
  f32x4 a0 = {0.f, 0.f, 0.f, 0.f}, a1 = {0.f, 0.f, 0.f, 0.f}, a2 = {0.f, 0.f, 0.f, 0.f};
#pragma unroll
  for (int step = 0; step < 2; ++step) {
    const int kb = step * 32 + q * 8;
    half8 aF = *(const half8*)&hl[c0][kb];
    half8 b0 = *(const half8*)(w2hT + (size_t)(c0)      * 64 + kb);
    half8 b1v = *(const half8*)(w2hT + (size_t)(c0 + 16) * 64 + kb);
    half8 b2 = *(const half8*)(w2hT + (size_t)(c0 + 32) * 64 + kb);
    a0 = __builtin_amdgcn_mfma_f32_16x16x32_f16(aF, b0, a0, 0, 0, 0);
    a1 = __builtin_amdgcn_mfma_f32_16x16x32_f16(aF, b1v, a1, 0, 0, 0);
    a2 = __builtin_amdgcn_mfma_f32_16x16x32_f16(aF, b2, a2, 0, 0, 0);
  }
#pragma unroll
  for (int j = 0; j < 4; ++j) {
    int orow = blockIdx.x * 16 + q * 4 + j;
    if (orow < N) {
      float dv = dinv[orow];
      __half* ph = h2h + (size_t)orow * 40;
      ph[c0]      = __float2half(a0[j] * dv);
      ph[c0 + 16] = __float2half(a1[j] * dv);
      if (c0 < 8) ph[c0 + 32] = __float2half(a2[j] * dv);
    }
  }
}

// ---- agg2: 8-lane-half row gathers from 80B rows; csr prefetch ----
__global__ __launch_bounds__(256) void k_agg2f(const __half* __restrict__ h2h,
    const int* __restrict__ rowptr, const int* __restrict__ csr,
    const float* __restrict__ dinv, const float* __restrict__ b2,
    float* __restrict__ out, int N) {
  const int t = threadIdx.x;
  const int r = t & 15;
  const int h = r >> 3;
  const int ro = r & 7;
  const int qq = (t >> 4) & 3;
  const int row = blockIdx.x * 16 + (t >> 4);
  if (row >= N) return;
  const int beg = rowptr[row], end = rowptr[row + 1];
  const bool act = (ro < 5);
  float acc[8] = {};
  if (h == 0 && act) HADD8(row, h2h, 40);  // self term
  int idx = (beg + r < end) ? csr[beg + r] : 0;
  for (int b = beg; b < end; b += 16) {
    int m = end - b; if (m > 16) m = 16;
    int idxn = (b + 16 + r < end) ? csr[b + 16 + r] : 0;
#pragma unroll
    for (int tt = 0; tt < 8; ++tt) {
      int e = 2 * tt + h;
      int s0 = __shfl(idx, qq * 16 + e);
      if (e < m && act) { HADD8(s0, h2h, 40); }
    }
    idx = idxn;
  }
#pragma unroll
  for (int i = 0; i < 8; ++i) acc[i] += __shfl_xor(acc[i], 8);
  if (h == 0 && act) {
    float4 ba = *(const float4*)(b2 + ro * 8);
    float4 bbv = *(const float4*)(b2 + ro * 8 + 4);
    float dv = dinv[row];
    float4 o0, o1;
    o0.x = dv * acc[0] + ba.x;  o0.y = dv * acc[1] + ba.y;
    o0.z = dv * acc[2] + ba.z;  o0.w = dv * acc[3] + ba.w;
    o1.x = dv * acc[4] + bbv.x; o1.y = dv * acc[5] + bbv.y;
    o1.z = dv * acc[6] + bbv.z; o1.w = dv * acc[7] + bbv.w;
    float* po = out + (size_t)row * 40 + ro * 8;
    *(float4*)po = o0;
    *(float4*)(po + 4) = o1;
  }
}

extern "C" void kernel_launch(void* const* d_in, const int* in_sizes, int n_in,
                              void* d_out, int out_size, void* d_ws, size_t ws_size,
                              hipStream_t stream) {
  const float* x  = (const float*)d_in[0];
  const int*   ei = (const int*)d_in[1];
  const float* W1 = (const float*)d_in[2];
  const float* b1 = (const float*)d_in[3];
  const float* W2 = (const float*)d_in[4];
  const float* b2 = (const float*)d_in[5];
  float* out = (float*)d_out;

  const int N = in_sizes[0] / 256;
  const int E = in_sizes[1] / 2;
  const int* src = ei;       // edge_index[0]
  const int* dst = ei + E;   // edge_index[1]

  const int nchunk = (E + CHUNK - 1) / CHUNK;   // 196
  const int nbuck  = (N + 255) >> BSH;          // 391

  // workspace layout (4B units; regions 128B-aligned)
  int* ws = (int*)d_ws;
  size_t o = 0;
  auto alignr = [](size_t v) { return (v + 31) & ~(size_t)31; };
  int* hist    = ws + o; o = alignr(o + (size_t)nchunk * nbuck);
  int* colsum  = ws + o; o = alignr(o + 512);
  int* bstart  = ws + o; o = alignr(o + nbuck + 1);
  int* ticket  = ws + o; o = alignr(o + 32);
  int* rowptr  = ws + o; o = alignr(o + (size_t)N + 1);
  float* dinv  = (float*)(ws + o); o = alignr(o + (size_t)N);
  int* csr     = ws + o; o = alignr(o + (size_t)E);
  _Float16* whT  = (_Float16*)(ws + o); o = alignr(o + 64 * 256 / 2);  // 32 KB
  _Float16* w2hT = (_Float16*)(ws + o); o = alignr(o + 48 * 64 / 2);   // 6 KB
  // region A: ebuf (E ints) then reused as h1h (N*64 half = N*32 int)
  size_t szA = (size_t)E; { size_t a2 = (size_t)N * 32; if (a2 > szA) szA = a2; }
  int*    ebuf = (int*)(ws + o);
  __half* h1h  = (__half*)(ws + o); o = alignr(o + szA);
  __half* h2h  = (__half*)(ws + o); o = alignr(o + (size_t)N * 20);  // stride-40 halfs

  k_hist    <<<nchunk, 256, 0, stream>>>(dst, hist, E, nbuck, W1, whT, W2, w2hT, ticket);
  k_scanA   <<<nbuck, 256, 0, stream>>>(hist, colsum, bstart, ticket, nchunk, nbuck, E);
  k_scatter2<<<nchunk, 256, 0, stream>>>(src, dst, hist, bstart, ebuf, E, nbuck);
  k_csr     <<<nbuck, 256, 0, stream>>>(ebuf, bstart, csr, rowptr, dinv, N, E, nbuck);

  int nwave = (N + 15) / 16;
  int ngb = (nwave + 3) / 4;
  k_gemm1 <<<ngb, 256, 0, stream>>>(x, whT, dinv, h1h, N);
  k_agg1g2<<<nwave, 256, 0, stream>>>(h1h, rowptr, csr, dinv, b1, w2hT, h2h, N);
  k_agg2f <<<nwave, 256, 0, stream>>>(h2h, rowptr, csr, dinv, b2, out, N);
}

// Round 12
// 163.233 us; speedup vs baseline: 1.3289x; 1.3289x over previous
//
#include <hip/hip_runtime.h>
#include <hip/hip_fp16.h>

// GCN 2-layer. fp16 MFMA GEMM1; agg1 fused with MFMA gemm2 (LDS tile);
// fp16 messages, fp32 accumulation; 2-rows-per-instruction dwordx4 gathers.
// CSR via bucket sort (no global atomics), packed 1-int edge buffer.
// Weight transpose folded into k_hist (R10 structure otherwise).

#define CHUNK 4096   // edges per hist/scatter block
#define BSH   8      // bucket = dst >> 8 (256 nodes per bucket)

typedef _Float16 half8 __attribute__((ext_vector_type(8)));
typedef float f32x4 __attribute__((ext_vector_type(4)));

// ---- 1. per-chunk bucket histogram (LDS atomics only) + weight transpose ----
__global__ __launch_bounds__(256) void k_hist(const int* __restrict__ dst,
    int* __restrict__ hist, int E, int nbuck,
    const float* __restrict__ W1, _Float16* __restrict__ whT,
    const float* __restrict__ W2, _Float16* __restrict__ w2hT) {
  __shared__ int h[512];
  const int t = threadIdx.x;
  for (int i = t; i < nbuck; i += 256) h[i] = 0;
  __syncthreads();
  int base = blockIdx.x * CHUNK;
  int lim = base + CHUNK < E ? base + CHUNK : E;
  for (int i = base + t; i < lim; i += 256)
    atomicAdd(&h[dst[i] >> BSH], 1);
  __syncthreads();
  for (int i = t; i < nbuck; i += 256)
    hist[(size_t)blockIdx.x * nbuck + i] = h[i];
  // fused weight prep (blocks 0..16 do small parallel side-work)
  if (blockIdx.x < 16) {           // W1 [256][64] -> whT [64][256]
    int d = blockIdx.x * 4 + (t >> 6);
    int k0 = (t & 63) * 4;
#pragma unroll
    for (int i = 0; i < 4; ++i)
      whT[(size_t)d * 256 + k0 + i] = (_Float16)W1[(size_t)(k0 + i) * 64 + d];
  } else if (blockIdx.x == 16) {   // W2 [64][40] -> w2hT [48][64] (pad 0)
    for (int i = t; i < 48 * 64; i += 256) {
      int dd = i >> 6, k = i & 63;
      w2hT[i] = (_Float16)(dd < 40 ? W2[(size_t)k * 40 + dd] : 0.f);
    }
  }
}

// ---- 2. per-bucket exclusive scan over chunks (in place); column totals ----
__global__ __launch_bounds__(256) void k_scanA(int* __restrict__ hist,
    int* __restrict__ colsum, int nchunk, int nbuck) {
  __shared__ int s[512];
  int b = blockIdx.x, t = threadIdx.x;
  s[t]       = (t < nchunk)       ? hist[(size_t)t * nbuck + b]         : 0;
  s[t + 256] = (t + 256 < nchunk) ? hist[(size_t)(t + 256) * nbuck + b] : 0;
  __syncthreads();
  for (int off = 1; off < 512; off <<= 1) {
    int a0 = (t >= off) ? s[t - off] : 0;
    int a1 = (t + 256 >= off) ? s[t + 256 - off] : 0;
    __syncthreads();
    s[t] += a0; s[t + 256] += a1;
    __syncthreads();
  }
  if (t < nchunk) hist[(size_t)t * nbuck + b] = t ? s[t - 1] : 0;
  if (t + 256 < nchunk) hist[(size_t)(t + 256) * nbuck + b] = s[t + 255];
  if (t == 0) colsum[b] = s[nchunk - 1];
}

// ---- 3. scan bucket totals -> bucket starts ----
__global__ __launch_bounds__(512) void k_scanB(const int* __restrict__ colsum,
    int* __restrict__ bstart, int nbuck, int E) {
  __shared__ int s[512];
  int t = threadIdx.x;
  s[t] = (t < nbuck) ? colsum[t] : 0;
  __syncthreads();
  for (int off = 1; off < 512; off <<= 1) {
    int a = (t >= off) ? s[t - off] : 0;
    __syncthreads();
    s[t] += a;
    __syncthreads();
  }
  if (t < nbuck) bstart[t] = t ? s[t - 1] : 0;
  if (t == 0) bstart[nbuck] = E;
}

// ---- 4. scatter edges into bucket-sorted packed ebuf (LDS cursors only) ----
// packed: (src << 8) | (dst & 255)   [src < 2^17]
__global__ __launch_bounds__(256) void k_scatter2(const int* __restrict__ src,
    const int* __restrict__ dst, const int* __restrict__ hist,
    const int* __restrict__ bstart, int* __restrict__ ebuf, int E, int nbuck) {
  __shared__ int cur[512];
  for (int i = threadIdx.x; i < nbuck; i += 256)
    cur[i] = bstart[i] + hist[(size_t)blockIdx.x * nbuck + i];
  __syncthreads();
  int base = blockIdx.x * CHUNK;
  int lim = base + CHUNK < E ? base + CHUNK : E;
  for (int i = base + threadIdx.x; i < lim; i += 256) {
    int d = dst[i];
    int pos = atomicAdd(&cur[d >> BSH], 1);
    ebuf[pos] = (src[i] << 8) | (d & 255);
  }
}

// ---- 5. per-bucket LDS counting sort -> csr, rowptr, dinv ----
__global__ __launch_bounds__(256) void k_csr(const int* __restrict__ ebuf,
    const int* __restrict__ bstart, int* __restrict__ csr, int* __restrict__ rowptr,
    float* __restrict__ dinv, int N, int E, int nbuck) {
  int b = blockIdx.x, t = threadIdx.x;
  int beg = bstart[b], end = bstart[b + 1];
  __shared__ int s[256];
  __shared__ int cur[256];
  s[t] = 0;
  __syncthreads();
  for (int i = beg + t; i < end; i += 256)
    atomicAdd(&s[ebuf[i] & 255], 1);
  __syncthreads();
  int cnt = s[t];
  for (int off = 1; off < 256; off <<= 1) {  // inclusive scan
    int a = (t >= off) ? s[t - off] : 0;
    __syncthreads();
    s[t] += a;
    __syncthreads();
  }
  int ex = t ? s[t - 1] : 0;
  cur[t] = beg + ex;
  int node = (b << BSH) + t;
  if (node < N) {
    rowptr[node] = beg + ex;
    dinv[node] = rsqrtf((float)cnt + 1.0f);  // +1 self-loop
  }
  if (b == 0 && t == 0) rowptr[N] = E;
  __syncthreads();
  for (int i = beg + t; i < end; i += 256) {
    int v = ebuf[i];
    int pos = atomicAdd(&cur[v & 255], 1);
    csr[pos] = (int)((unsigned)v >> 8);
  }
}

// ---- GEMM1 via MFMA f16: wave = 16 rows x 64 cols, K=256; all x loads hoisted ----
__global__ __launch_bounds__(256) void k_gemm1(const float* __restrict__ x,
    const _Float16* __restrict__ whT, const float* __restrict__ dinv,
    __half* __restrict__ h1h, int N) {
  const int l = threadIdx.x & 63;
  const int wid = threadIdx.x >> 6;
  const int r0 = (blockIdx.x * 4 + wid) * 16;
  if (r0 >= N) return;
  const int c0 = l & 15;
  const int q = l >> 4;
  int arow = r0 + c0; if (arow >= N) arow = N - 1;
  const float* xp = x + (size_t)arow * 256 + q * 8;
  float4 xv[8][2];
#pragma unroll
  for (int step = 0; step < 8; ++step) {
    xv[step][0] = *(const float4*)(xp + step * 32);
    xv[step][1] = *(const float4*)(xp + step * 32 + 4);
  }
  f32x4 acc0 = {0.f, 0.f, 0.f, 0.f}, acc1 = {0.f, 0.f, 0.f, 0.f};
  f32x4 acc2 = {0.f, 0.f, 0.f, 0.f}, acc3 = {0.f, 0.f, 0.f, 0.f};
#pragma unroll
  for (int step = 0; step < 8; ++step) {
    const int kb = step * 32 + q * 8;
    half8 aF;
    aF[0] = (_Float16)xv[step][0].x; aF[1] = (_Float16)xv[step][0].y;
    aF[2] = (_Float16)xv[step][0].z; aF[3] = (_Float16)xv[step][0].w;
    aF[4] = (_Float16)xv[step][1].x; aF[5] = (_Float16)xv[step][1].y;
    aF[6] = (_Float16)xv[step][1].z; aF[7] = (_Float16)xv[step][1].w;
    half8 b0 = *(const half8*)(whT + (size_t)(c0)      * 256 + kb);
    half8 b1 = *(const half8*)(whT + (size_t)(c0 + 16) * 256 + kb);
    half8 b2 = *(const half8*)(whT + (size_t)(c0 + 32) * 256 + kb);
    half8 b3 = *(const half8*)(whT + (size_t)(c0 + 48) * 256 + kb);
    acc0 = __builtin_amdgcn_mfma_f32_16x16x32_f16(aF, b0, acc0, 0, 0, 0);
    acc1 = __builtin_amdgcn_mfma_f32_16x16x32_f16(aF, b1, acc1, 0, 0, 0);
    acc2 = __builtin_amdgcn_mfma_f32_16x16x32_f16(aF, b2, acc2, 0, 0, 0);
    acc3 = __builtin_amdgcn_mfma_f32_16x16x32_f16(aF, b3, acc3, 0, 0, 0);
  }
#pragma unroll
  for (int j = 0; j < 4; ++j) {
    int row = r0 + q * 4 + j;
    if (row < N) {
      float dv = dinv[row];
      __half* ph = h1h + (size_t)row * 64 + c0;
      ph[0]  = __float2half(acc0[j] * dv);
      ph[16] = __float2half(acc1[j] * dv);
      ph[32] = __float2half(acc2[j] * dv);
      ph[48] = __float2half(acc3[j] * dv);
    }
  }
}

// add full 16B (8 halfs) of row S at half-offset ro*8 into acc[0..7]
#define HADD8(S, HPTR, STRIDE) { \
  uint4 u_ = *(const uint4*)((HPTR) + (size_t)(S) * (STRIDE) + ro * 8); \
  union { unsigned v; __half2 h; } p0_, p1_, p2_, p3_; \
  p0_.v = u_.x; p1_.v = u_.y; p2_.v = u_.z; p3_.v = u_.w; \
  float2 f0_ = __half22float2(p0_.h), f1_ = __half22float2(p1_.h); \
  float2 f2_ = __half22float2(p2_.h), f3_ = __half22float2(p3_.h); \
  acc[0] += f0_.x; acc[1] += f0_.y; acc[2] += f1_.x; acc[3] += f1_.y; \
  acc[4] += f2_.x; acc[5] += f2_.y; acc[6] += f3_.x; acc[7] += f3_.y; }

// ---- fused agg1 + gemm2: block = 16 dst rows; 8-lane-half row gathers;
//      hrelu -> LDS tile -> wave0 MFMA (16x48, K=64) -> h2h (stride 40) ----
__global__ __launch_bounds__(256) void k_agg1g2(const __half* __restrict__ h1h,
    const int* __restrict__ rowptr, const int* __restrict__ csr,
    const float* __restrict__ dinv, const float* __restrict__ b1,
    const _Float16* __restrict__ w2hT, __half* __restrict__ h2h, int N) {
  __shared__ _Float16 hl[16][72];
  const int t = threadIdx.x;
  const int r = t & 15;        // lane within quarter
  const int h = r >> 3;        // half-group: row parity
  const int ro = r & 7;        // 16B chunk owner: dims ro*8..+8
  const int qq = (t >> 4) & 3; // quarter within wave
  const int qidx = t >> 4;     // row slot within block
  const int row = blockIdx.x * 16 + qidx;
  const int rowc = row < N ? row : N - 1;
  const int beg = rowptr[rowc], end = (row < N) ? rowptr[rowc + 1] : beg;
  float acc[8] = {};
  if (h == 0) HADD8(rowc, h1h, 64);  // self term, exactly once
  for (int b = beg; b < end; b += 16) {
    int m = end - b; if (m > 16) m = 16;
    int idx = (r < m) ? csr[b + r] : 0;
#pragma unroll
    for (int tt = 0; tt < 8; ++tt) {
      int e = 2 * tt + h;
      int s0 = __shfl(idx, qq * 16 + e);
      if (e < m) { HADD8(s0, h1h, 64); }
    }
  }
#pragma unroll
  for (int i = 0; i < 8; ++i) acc[i] += __shfl_xor(acc[i], 8);
  if (h == 0) {
    float4 ba = *(const float4*)(b1 + ro * 8);
    float4 bbv = *(const float4*)(b1 + ro * 8 + 4);
    float dv = dinv[rowc];
    half8 hv;
    hv[0] = (_Float16)fmaxf(dv * acc[0] + ba.x, 0.f);
    hv[1] = (_Float16)fmaxf(dv * acc[1] + ba.y, 0.f);
    hv[2] = (_Float16)fmaxf(dv * acc[2] + ba.z, 0.f);
    hv[3] = (_Float16)fmaxf(dv * acc[3] + ba.w, 0.f);
    hv[4] = (_Float16)fmaxf(dv * acc[4] + bbv.x, 0.f);
    hv[5] = (_Float16)fmaxf(dv * acc[5] + bbv.y, 0.f);
    hv[6] = (_Float16)fmaxf(dv * acc[6] + bbv.z, 0.f);
    hv[7] = (_Float16)fmaxf(dv * acc[7] + bbv.w, 0.f);
    *(half8*)&hl[qidx][ro * 8] = hv;
  }
  __syncthreads();
  if (t >= 64) return;  // wave 0 does the 16x48 GEMM
  const int c0 = t & 15;
  const int q = t >> 4;
  f32x4 a0 = {0.f, 0.f, 0.f, 0.f}, a1 = {0.f, 0.f, 0.f, 0.f}, a2 = {0.f, 0.f, 0.f, 0.f};
#pragma unroll
  for (int step = 0; step < 2; ++step) {
    const int kb = step * 32 + q * 8;
    half8 aF = *(const half8*)&hl[c0][kb];
    half8 b0 = *(const half8*)(w2hT + (size_t)(c0)      * 64 + kb);
    half8 b1v = *(const half8*)(w2hT + (size_t)(c0 + 16) * 64 + kb);
    half8 b2 = *(const half8*)(w2hT + (size_t)(c0 + 32) * 64 + kb);
    a0 = __builtin_amdgcn_mfma_f32_16x16x32_f16(aF, b0, a0, 0, 0, 0);
    a1 = __builtin_amdgcn_mfma_f32_16x16x32_f16(aF, b1v, a1, 0, 0, 0);
    a2 = __builtin_amdgcn_mfma_f32_16x16x32_f16(aF, b2, a2, 0, 0, 0);
  }
#pragma unroll
  for (int j = 0; j < 4; ++j) {
    int orow = blockIdx.x * 16 + q * 4 + j;
    if (orow < N) {
      float dv = dinv[orow];
      __half* ph = h2h + (size_t)orow * 40;
      ph[c0]      = __float2half(a0[j] * dv);
      ph[c0 + 16] = __float2half(a1[j] * dv);
      if (c0 < 8) ph[c0 + 32] = __float2half(a2[j] * dv);
    }
  }
}

// ---- agg2: 8-lane-half row gathers from 80B rows (OUT=40, lanes ro<5) ----
__global__ __launch_bounds__(256) void k_agg2f(const __half* __restrict__ h2h,
    const int* __restrict__ rowptr, const int* __restrict__ csr,
    const float* __restrict__ dinv, const float* __restrict__ b2,
    float* __restrict__ out, int N) {
  const int t = threadIdx.x;
  const int r = t & 15;
  const int h = r >> 3;
  const int ro = r & 7;
  const int qq = (t >> 4) & 3;
  const int row = blockIdx.x * 16 + (t >> 4);
  if (row >= N) return;
  const int beg = rowptr[row], end = rowptr[row + 1];
  const bool act = (ro < 5);
  float acc[8] = {};
  if (h == 0 && act) HADD8(row, h2h, 40);  // self term
  for (int b = beg; b < end; b += 16) {
    int m = end - b; if (m > 16) m = 16;
    int idx = (r < m) ? csr[b + r] : 0;
#pragma unroll
    for (int tt = 0; tt < 8; ++tt) {
      int e = 2 * tt + h;
      int s0 = __shfl(idx, qq * 16 + e);
      if (e < m && act) { HADD8(s0, h2h, 40); }
    }
  }
#pragma unroll
  for (int i = 0; i < 8; ++i) acc[i] += __shfl_xor(acc[i], 8);
  if (h == 0 && act) {
    float4 ba = *(const float4*)(b2 + ro * 8);
    float4 bbv = *(const float4*)(b2 + ro * 8 + 4);
    float dv = dinv[row];
    float4 o0, o1;
    o0.x = dv * acc[0] + ba.x;  o0.y = dv * acc[1] + ba.y;
    o0.z = dv * acc[2] + ba.z;  o0.w = dv * acc[3] + ba.w;
    o1.x = dv * acc[4] + bbv.x; o1.y = dv * acc[5] + bbv.y;
    o1.z = dv * acc[6] + bbv.z; o1.w = dv * acc[7] + bbv.w;
    float* po = out + (size_t)row * 40 + ro * 8;
    *(float4*)po = o0;
    *(float4*)(po + 4) = o1;
  }
}

extern "C" void kernel_launch(void* const* d_in, const int* in_sizes, int n_in,
                              void* d_out, int out_size, void* d_ws, size_t ws_size,
                              hipStream_t stream) {
  const float* x  = (const float*)d_in[0];
  const int*   ei = (const int*)d_in[1];
  const float* W1 = (const float*)d_in[2];
  const float* b1 = (const float*)d_in[3];
  const float* W2 = (const float*)d_in[4];
  const float* b2 = (const float*)d_in[5];
  float* out = (float*)d_out;

  const int N = in_sizes[0] / 256;
  const int E = in_sizes[1] / 2;
  const int* src = ei;       // edge_index[0]
  const int* dst = ei + E;   // edge_index[1]

  const int nchunk = (E + CHUNK - 1) / CHUNK;   // 391
  const int nbuck  = (N + 255) >> BSH;          // 391

  // workspace layout (4B units; regions 128B-aligned)
  int* ws = (int*)d_ws;
  size_t o = 0;
  auto alignr = [](size_t v) { return (v + 31) & ~(size_t)31; };
  int* hist    = ws + o; o = alignr(o + (size_t)nchunk * nbuck);
  int* colsum  = ws + o; o = alignr(o + 512);
  int* bstart  = ws + o; o = alignr(o + nbuck + 1);
  int* rowptr  = ws + o; o = alignr(o + (size_t)N + 1);
  float* dinv  = (float*)(ws + o); o = alignr(o + (size_t)N);
  int* csr     = ws + o; o = alignr(o + (size_t)E);
  _Float16* whT  = (_Float16*)(ws + o); o = alignr(o + 64 * 256 / 2);  // 32 KB
  _Float16* w2hT = (_Float16*)(ws + o); o = alignr(o + 48 * 64 / 2);   // 6 KB
  // region A: ebuf (E ints) then reused as h1h (N*64 half = N*32 int)
  size_t szA = (size_t)E; { size_t a2 = (size_t)N * 32; if (a2 > szA) szA = a2; }
  int*    ebuf = (int*)(ws + o);
  __half* h1h  = (__half*)(ws + o); o = alignr(o + szA);
  __half* h2h  = (__half*)(ws + o); o = alignr(o + (size_t)N * 20);  // stride-40 halfs

  k_hist    <<<nchunk, 256, 0, stream>>>(dst, hist, E, nbuck, W1, whT, W2, w2hT);
  k_scanA   <<<nbuck, 256, 0, stream>>>(hist, colsum, nchunk, nbuck);
  k_scanB   <<<1, 512, 0, stream>>>(colsum, bstart, nbuck, E);
  k_scatter2<<<nchunk, 256, 0, stream>>>(src, dst, hist, bstart, ebuf, E, nbuck);
  k_csr     <<<nbuck, 256, 0, stream>>>(ebuf, bstart, csr, rowptr, dinv, N, E, nbuck);

  int nwave = (N + 15) / 16;
  int ngb = (nwave + 3) / 4;
  k_gemm1 <<<ngb, 256, 0, stream>>>(x, whT, dinv, h1h, N);
  k_agg1g2<<<nwave, 256, 0, stream>>>(h1h, rowptr, csr, dinv, b1, w2hT, h2h, N);
  k_agg2f <<<nwave, 256, 0, stream>>>(h2h, rowptr, csr, dinv, b2, out, N);
}

// Round 13
// 162.039 us; speedup vs baseline: 1.3387x; 1.0074x over previous
//
#include <hip/hip_runtime.h>
#include <hip/hip_fp16.h>

// GCN 2-layer. fp16 MFMA GEMM1 (unscaled, merged into scanA's grid);
// agg1 applies dinv[src] in-gather (FMA) and fuses MFMA gemm2 via LDS tile;
// fp16 messages, fp32 accumulation; 2-rows-per-instruction dwordx4 gathers.
// CSR via bucket sort (no global atomics), packed 1-int edge buffer.

#define CHUNK 4096   // edges per hist/scatter block
#define BSH   8      // bucket = dst >> 8 (256 nodes per bucket)

typedef _Float16 half8 __attribute__((ext_vector_type(8)));
typedef float f32x4 __attribute__((ext_vector_type(4)));

// ---- 1. per-chunk bucket histogram (LDS atomics only) + weight transpose ----
__global__ __launch_bounds__(256) void k_hist(const int* __restrict__ dst,
    int* __restrict__ hist, int E, int nbuck,
    const float* __restrict__ W1, _Float16* __restrict__ whT,
    const float* __restrict__ W2, _Float16* __restrict__ w2hT) {
  __shared__ int h[512];
  const int t = threadIdx.x;
  for (int i = t; i < nbuck; i += 256) h[i] = 0;
  __syncthreads();
  int base = blockIdx.x * CHUNK;
  int lim = base + CHUNK < E ? base + CHUNK : E;
  for (int i = base + t; i < lim; i += 256)
    atomicAdd(&h[dst[i] >> BSH], 1);
  __syncthreads();
  for (int i = t; i < nbuck; i += 256)
    hist[(size_t)blockIdx.x * nbuck + i] = h[i];
  // fused weight prep (blocks 0..16 do small parallel side-work)
  if (blockIdx.x < 16) {           // W1 [256][64] -> whT [64][256]
    int d = blockIdx.x * 4 + (t >> 6);
    int k0 = (t & 63) * 4;
#pragma unroll
    for (int i = 0; i < 4; ++i)
      whT[(size_t)d * 256 + k0 + i] = (_Float16)W1[(size_t)(k0 + i) * 64 + d];
  } else if (blockIdx.x == 16) {   // W2 [64][40] -> w2hT [48][64] (pad 0)
    for (int i = t; i < 48 * 64; i += 256) {
      int dd = i >> 6, k = i & 63;
      w2hT[i] = (_Float16)(dd < 40 ? W2[(size_t)k * 40 + dd] : 0.f);
    }
  }
}

// ---- 2. merged: blocks [0,nbuck) = per-bucket scan; blocks >= nbuck = GEMM1 ----
// GEMM1 via MFMA f16: wave = 16 rows x 64 cols, K=256; h1h = fp16(x@W1) UNSCALED
__global__ __launch_bounds__(256) void k_scanA_g1(int* __restrict__ hist,
    int* __restrict__ colsum, int nchunk, int nbuck,
    const float* __restrict__ x, const _Float16* __restrict__ whT,
    __half* __restrict__ h1h, int N) {
  __shared__ int s[512];
  const int t = threadIdx.x;
  if (blockIdx.x >= (unsigned)nbuck) {
    // ---------------- GEMM1 part ----------------
    const int gb = blockIdx.x - nbuck;
    const int l = t & 63;
    const int wid = t >> 6;
    const int r0 = (gb * 4 + wid) * 16;
    if (r0 >= N) return;
    const int c0 = l & 15;
    const int q = l >> 4;
    int arow = r0 + c0; if (arow >= N) arow = N - 1;
    const float* xp = x + (size_t)arow * 256 + q * 8;
    float4 xv[8][2];
#pragma unroll
    for (int step = 0; step < 8; ++step) {
      xv[step][0] = *(const float4*)(xp + step * 32);
      xv[step][1] = *(const float4*)(xp + step * 32 + 4);
    }
    f32x4 acc0 = {0.f, 0.f, 0.f, 0.f}, acc1 = {0.f, 0.f, 0.f, 0.f};
    f32x4 acc2 = {0.f, 0.f, 0.f, 0.f}, acc3 = {0.f, 0.f, 0.f, 0.f};
#pragma unroll
    for (int step = 0; step < 8; ++step) {
      const int kb = step * 32 + q * 8;
      half8 aF;
      aF[0] = (_Float16)xv[step][0].x; aF[1] = (_Float16)xv[step][0].y;
      aF[2] = (_Float16)xv[step][0].z; aF[3] = (_Float16)xv[step][0].w;
      aF[4] = (_Float16)xv[step][1].x; aF[5] = (_Float16)xv[step][1].y;
      aF[6] = (_Float16)xv[step][1].z; aF[7] = (_Float16)xv[step][1].w;
      half8 b0 = *(const half8*)(whT + (size_t)(c0)      * 256 + kb);
      half8 b1 = *(const half8*)(whT + (size_t)(c0 + 16) * 256 + kb);
      half8 b2 = *(const half8*)(whT + (size_t)(c0 + 32) * 256 + kb);
      half8 b3 = *(const half8*)(whT + (size_t)(c0 + 48) * 256 + kb);
      acc0 = __builtin_amdgcn_mfma_f32_16x16x32_f16(aF, b0, acc0, 0, 0, 0);
      acc1 = __builtin_amdgcn_mfma_f32_16x16x32_f16(aF, b1, acc1, 0, 0, 0);
      acc2 = __builtin_amdgcn_mfma_f32_16x16x32_f16(aF, b2, acc2, 0, 0, 0);
      acc3 = __builtin_amdgcn_mfma_f32_16x16x32_f16(aF, b3, acc3, 0, 0, 0);
    }
    // C/D: col = lane&15 (+16n), row = (lane>>4)*4 + j
#pragma unroll
    for (int j = 0; j < 4; ++j) {
      int row = r0 + q * 4 + j;
      if (row < N) {
        __half* ph = h1h + (size_t)row * 64 + c0;
        ph[0]  = __float2half(acc0[j]);
        ph[16] = __float2half(acc1[j]);
        ph[32] = __float2half(acc2[j]);
        ph[48] = __float2half(acc3[j]);
      }
    }
    return;
  }
  // ---------------- scanA part ----------------
  int b = blockIdx.x;
  s[t]       = (t < nchunk)       ? hist[(size_t)t * nbuck + b]         : 0;
  s[t + 256] = (t + 256 < nchunk) ? hist[(size_t)(t + 256) * nbuck + b] : 0;
  __syncthreads();
  for (int off = 1; off < 512; off <<= 1) {
    int a0 = (t >= off) ? s[t - off] : 0;
    int a1 = (t + 256 >= off) ? s[t + 256 - off] : 0;
    __syncthreads();
    s[t] += a0; s[t + 256] += a1;
    __syncthreads();
  }
  if (t < nchunk) hist[(size_t)t * nbuck + b] = t ? s[t - 1] : 0;
  if (t + 256 < nchunk) hist[(size_t)(t + 256) * nbuck + b] = s[t + 255];
  if (t == 0) colsum[b] = s[nchunk - 1];
}

// ---- 3. scan bucket totals -> bucket starts ----
__global__ __launch_bounds__(512) void k_scanB(const int* __restrict__ colsum,
    int* __restrict__ bstart, int nbuck, int E) {
  __shared__ int s[512];
  int t = threadIdx.x;
  s[t] = (t < nbuck) ? colsum[t] : 0;
  __syncthreads();
  for (int off = 1; off < 512; off <<= 1) {
    int a = (t >= off) ? s[t - off] : 0;
    __syncthreads();
    s[t] += a;
    __syncthreads();
  }
  if (t < nbuck) bstart[t] = t ? s[t - 1] : 0;
  if (t == 0) bstart[nbuck] = E;
}

// ---- 4. scatter edges into bucket-sorted packed ebuf (LDS cursors only) ----
// packed: (src << 8) | (dst & 255)   [src < 2^17]
__global__ __launch_bounds__(256) void k_scatter2(const int* __restrict__ src,
    const int* __restrict__ dst, const int* __restrict__ hist,
    const int* __restrict__ bstart, int* __restrict__ ebuf, int E, int nbuck) {
  __shared__ int cur[512];
  for (int i = threadIdx.x; i < nbuck; i += 256)
    cur[i] = bstart[i] + hist[(size_t)blockIdx.x * nbuck + i];
  __syncthreads();
  int base = blockIdx.x * CHUNK;
  int lim = base + CHUNK < E ? base + CHUNK : E;
  for (int i = base + threadIdx.x; i < lim; i += 256) {
    int d = dst[i];
    int pos = atomicAdd(&cur[d >> BSH], 1);
    ebuf[pos] = (src[i] << 8) | (d & 255);
  }
}

// ---- 5. per-bucket LDS counting sort -> csr, rowptr, dinv ----
__global__ __launch_bounds__(256) void k_csr(const int* __restrict__ ebuf,
    const int* __restrict__ bstart, int* __restrict__ csr, int* __restrict__ rowptr,
    float* __restrict__ dinv, int N, int E, int nbuck) {
  int b = blockIdx.x, t = threadIdx.x;
  int beg = bstart[b], end = bstart[b + 1];
  __shared__ int s[256];
  __shared__ int cur[256];
  s[t] = 0;
  __syncthreads();
  for (int i = beg + t; i < end; i += 256)
    atomicAdd(&s[ebuf[i] & 255], 1);
  __syncthreads();
  int cnt = s[t];
  for (int off = 1; off < 256; off <<= 1) {  // inclusive scan
    int a = (t >= off) ? s[t - off] : 0;
    __syncthreads();
    s[t] += a;
    __syncthreads();
  }
  int ex = t ? s[t - 1] : 0;
  cur[t] = beg + ex;
  int node = (b << BSH) + t;
  if (node < N) {
    rowptr[node] = beg + ex;
    dinv[node] = rsqrtf((float)cnt + 1.0f);  // +1 self-loop
  }
  if (b == 0 && t == 0) rowptr[N] = E;
  __syncthreads();
  for (int i = beg + t; i < end; i += 256) {
    int v = ebuf[i];
    int pos = atomicAdd(&cur[v & 255], 1);
    csr[pos] = (int)((unsigned)v >> 8);
  }
}

// FMA-accumulate 16B (8 halfs) of row S, scaled by SC, into acc[0..7]
#define HFMA8(S, SC, HPTR, STRIDE) { \
  uint4 u_ = *(const uint4*)((HPTR) + (size_t)(S) * (STRIDE) + ro * 8); \
  union { unsigned v; __half2 h; } p0_, p1_, p2_, p3_; \
  p0_.v = u_.x; p1_.v = u_.y; p2_.v = u_.z; p3_.v = u_.w; \
  float2 f0_ = __half22float2(p0_.h), f1_ = __half22float2(p1_.h); \
  float2 f2_ = __half22float2(p2_.h), f3_ = __half22float2(p3_.h); \
  acc[0] += (SC) * f0_.x; acc[1] += (SC) * f0_.y; \
  acc[2] += (SC) * f1_.x; acc[3] += (SC) * f1_.y; \
  acc[4] += (SC) * f2_.x; acc[5] += (SC) * f2_.y; \
  acc[6] += (SC) * f3_.x; acc[7] += (SC) * f3_.y; }

// add full 16B (8 halfs) of row S at half-offset ro*8 into acc[0..7]
#define HADD8(S, HPTR, STRIDE) { \
  uint4 u_ = *(const uint4*)((HPTR) + (size_t)(S) * (STRIDE) + ro * 8); \
  union { unsigned v; __half2 h; } p0_, p1_, p2_, p3_; \
  p0_.v = u_.x; p1_.v = u_.y; p2_.v = u_.z; p3_.v = u_.w; \
  float2 f0_ = __half22float2(p0_.h), f1_ = __half22float2(p1_.h); \
  float2 f2_ = __half22float2(p2_.h), f3_ = __half22float2(p3_.h); \
  acc[0] += f0_.x; acc[1] += f0_.y; acc[2] += f1_.x; acc[3] += f1_.y; \
  acc[4] += f2_.x; acc[5] += f2_.y; acc[6] += f3_.x; acc[7] += f3_.y; }

// ---- fused agg1 + gemm2: block = 16 dst rows; 8-lane-half row gathers with
//      per-src dinv FMA; hrelu -> LDS tile -> wave0 MFMA -> h2h (stride 40) ----
__global__ __launch_bounds__(256) void k_agg1g2(const __half* __restrict__ h1h,
    const int* __restrict__ rowptr, const int* __restrict__ csr,
    const float* __restrict__ dinv, const float* __restrict__ b1,
    const _Float16* __restrict__ w2hT, __half* __restrict__ h2h, int N) {
  __shared__ _Float16 hl[16][72];
  const int t = threadIdx.x;
  const int r = t & 15;        // lane within quarter
  const int h = r >> 3;        // half-group: row parity
  const int ro = r & 7;        // 16B chunk owner: dims ro*8..+8
  const int qq = (t >> 4) & 3; // quarter within wave
  const int qidx = t >> 4;     // row slot within block
  const int row = blockIdx.x * 16 + qidx;
  const int rowc = row < N ? row : N - 1;
  const int beg = rowptr[rowc], end = (row < N) ? rowptr[rowc + 1] : beg;
  const float dv = dinv[rowc];
  float acc[8] = {};
  if (h == 0) HFMA8(rowc, dv, h1h, 64);  // self term (scaled), exactly once
  for (int b = beg; b < end; b += 16) {
    int m = end - b; if (m > 16) m = 16;
    int idx = (r < m) ? csr[b + r] : 0;
    float dvs = (r < m) ? dinv[idx] : 0.f;
#pragma unroll
    for (int tt = 0; tt < 8; ++tt) {
      int e = 2 * tt + h;
      int s0 = __shfl(idx, qq * 16 + e);
      float sc0 = __shfl(dvs, qq * 16 + e);
      if (e < m) { HFMA8(s0, sc0, h1h, 64); }
    }
  }
#pragma unroll
  for (int i = 0; i < 8; ++i) acc[i] += __shfl_xor(acc[i], 8);
  if (h == 0) {
    float4 ba = *(const float4*)(b1 + ro * 8);
    float4 bbv = *(const float4*)(b1 + ro * 8 + 4);
    half8 hv;
    hv[0] = (_Float16)fmaxf(dv * acc[0] + ba.x, 0.f);
    hv[1] = (_Float16)fmaxf(dv * acc[1] + ba.y, 0.f);
    hv[2] = (_Float16)fmaxf(dv * acc[2] + ba.z, 0.f);
    hv[3] = (_Float16)fmaxf(dv * acc[3] + ba.w, 0.f);
    hv[4] = (_Float16)fmaxf(dv * acc[4] + bbv.x, 0.f);
    hv[5] = (_Float16)fmaxf(dv * acc[5] + bbv.y, 0.f);
    hv[6] = (_Float16)fmaxf(dv * acc[6] + bbv.z, 0.f);
    hv[7] = (_Float16)fmaxf(dv * acc[7] + bbv.w, 0.f);
    *(half8*)&hl[qidx][ro * 8] = hv;
  }
  __syncthreads();
  if (t >= 64) return;  // wave 0 does the 16x48 GEMM
  const int c0 = t & 15;
  const int q = t >> 4;
  f32x4 a0 = {0.f, 0.f, 0.f, 0.f}, a1 = {0.f, 0.f, 0.f, 0.f}, a2 = {0.f, 0.f, 0.f, 0.f};
#pragma unroll
  for (int step = 0; step < 2; ++step) {
    const int kb = step * 32 + q * 8;
    half8 aF = *(const half8*)&hl[c0][kb];
    half8 b0 = *(const half8*)(w2hT + (size_t)(c0)      * 64 + kb);
    half8 b1v = *(const half8*)(w2hT + (size_t)(c0 + 16) * 64 + kb);
    half8 b2 = *(const half8*)(w2hT + (size_t)(c0 + 32) * 64 + kb);
    a0 = __builtin_amdgcn_mfma_f32_16x16x32_f16(aF, b0, a0, 0, 0, 0);
    a1 = __builtin_amdgcn_mfma_f32_16x16x32_f16(aF, b1v, a1, 0, 0, 0);
    a2 = __builtin_amdgcn_mfma_f32_16x16x32_f16(aF, b2, a2, 0, 0, 0);
  }
#pragma unroll
  for (int j = 0; j < 4; ++j) {
    int orow = blockIdx.x * 16 + q * 4 + j;
    if (orow < N) {
      float dvo = dinv[orow];
      __half* ph = h2h + (size_t)orow * 40;
      ph[c0]      = __float2half(a0[j] * dvo);
      ph[c0 + 16] = __float2half(a1[j] * dvo);
      if (c0 < 8) ph[c0 + 32] = __float2half(a2[j] * dvo);
    }
  }
}

// ---- agg2: 8-lane-half row gathers from 80B rows (OUT=40, lanes ro<5) ----
__global__ __launch_bounds__(256) void k_agg2f(const __half* __restrict__ h2h,
    const int* __restrict__ rowptr, const int* __restrict__ csr,
    const float* __restrict__ dinv, const float* __restrict__ b2,
    float* __restrict__ out, int N) {
  const int t = threadIdx.x;
  const int r = t & 15;
  const int h = r >> 3;
  const int ro = r & 7;
  const int qq = (t >> 4) & 3;
  const int row = blockIdx.x * 16 + (t >> 4);
  if (row >= N) return;
  const int beg = rowptr[row], end = rowptr[row + 1];
  const bool act = (ro < 5);
  float acc[8] = {};
  if (h == 0 && act) HADD8(row, h2h, 40);  // self term (h2h pre-scaled)
  for (int b = beg; b < end; b += 16) {
    int m = end - b; if (m > 16) m = 16;
    int idx = (r < m) ? csr[b + r] : 0;
#pragma unroll
    for (int tt = 0; tt < 8; ++tt) {
      int e = 2 * tt + h;
      int s0 = __shfl(idx, qq * 16 + e);
      if (e < m && act) { HADD8(s0, h2h, 40); }
    }
  }
#pragma unroll
  for (int i = 0; i < 8; ++i) acc[i] += __shfl_xor(acc[i], 8);
  if (h == 0 && act) {
    float4 ba = *(const float4*)(b2 + ro * 8);
    float4 bbv = *(const float4*)(b2 + ro * 8 + 4);
    float dv = dinv[row];
    float4 o0, o1;
    o0.x = dv * acc[0] + ba.x;  o0.y = dv * acc[1] + ba.y;
    o0.z = dv * acc[2] + ba.z;  o0.w = dv * acc[3] + ba.w;
    o1.x = dv * acc[4] + bbv.x; o1.y = dv * acc[5] + bbv.y;
    o1.z = dv * acc[6] + bbv.z; o1.w = dv * acc[7] + bbv.w;
    float* po = out + (size_t)row * 40 + ro * 8;
    *(float4*)po = o0;
    *(float4*)(po + 4) = o1;
  }
}

extern "C" void kernel_launch(void* const* d_in, const int* in_sizes, int n_in,
                              void* d_out, int out_size, void* d_ws, size_t ws_size,
                              hipStream_t stream) {
  const float* x  = (const float*)d_in[0];
  const int*   ei = (const int*)d_in[1];
  const float* W1 = (const float*)d_in[2];
  const float* b1 = (const float*)d_in[3];
  const float* W2 = (const float*)d_in[4];
  const float* b2 = (const float*)d_in[5];
  float* out = (float*)d_out;

  const int N = in_sizes[0] / 256;
  const int E = in_sizes[1] / 2;
  const int* src = ei;       // edge_index[0]
  const int* dst = ei + E;   // edge_index[1]

  const int nchunk = (E + CHUNK - 1) / CHUNK;   // 391
  const int nbuck  = (N + 255) >> BSH;          // 391

  // workspace layout (4B units; regions 128B-aligned)
  int* ws = (int*)d_ws;
  size_t o = 0;
  auto alignr = [](size_t v) { return (v + 31) & ~(size_t)31; };
  int* hist    = ws + o; o = alignr(o + (size_t)nchunk * nbuck);
  int* colsum  = ws + o; o = alignr(o + 512);
  int* bstart  = ws + o; o = alignr(o + nbuck + 1);
  int* rowptr  = ws + o; o = alignr(o + (size_t)N + 1);
  float* dinv  = (float*)(ws + o); o = alignr(o + (size_t)N);
  int* csr     = ws + o; o = alignr(o + (size_t)E);
  _Float16* whT  = (_Float16*)(ws + o); o = alignr(o + 64 * 256 / 2);  // 32 KB
  _Float16* w2hT = (_Float16*)(ws + o); o = alignr(o + 48 * 64 / 2);   // 6 KB
  int*    ebuf = (int*)(ws + o);       o = alignr(o + (size_t)E);      // no alias:
  __half* h1h  = (__half*)(ws + o);    o = alignr(o + (size_t)N * 32); // gemm1 runs early
  __half* h2h  = (__half*)(ws + o);    o = alignr(o + (size_t)N * 20); // stride-40 halfs

  int nwave = (N + 15) / 16;
  int ngb = (nwave + 3) / 4;

  k_hist    <<<nchunk, 256, 0, stream>>>(dst, hist, E, nbuck, W1, whT, W2, w2hT);
  k_scanA_g1<<<nbuck + ngb, 256, 0, stream>>>(hist, colsum, nchunk, nbuck,
                                              x, whT, h1h, N);
  k_scanB   <<<1, 512, 0, stream>>>(colsum, bstart, nbuck, E);
  k_scatter2<<<nchunk, 256, 0, stream>>>(src, dst, hist, bstart, ebuf, E, nbuck);
  k_csr     <<<nbuck, 256, 0, stream>>>(ebuf, bstart, csr, rowptr, dinv, N, E, nbuck);

  k_agg1g2<<<nwave, 256, 0, stream>>>(h1h, rowptr, csr, dinv, b1, w2hT, h2h, N);
  k_agg2f <<<nwave, 256, 0, stream>>>(h2h, rowptr, csr, dinv, b2, out, N);
}